// Round 12
// baseline (282.809 us; speedup 1.0000x reference)
//
#include <hip/hip_runtime.h>
#include <hip/hip_bf16.h>
#include <stdint.h>

#define ENC_DIM 2048
#define DEC_DIM 512
#define ATT_DIM 512
#define BATCH   256
#define PIX     196
#define M_TOTAL (BATCH*PIX)   // 50176
#define NT      (ENC_DIM/64)  // 32 K-tiles

typedef unsigned short u16;
typedef __attribute__((ext_vector_type(8))) short  bf16x8;
typedef __attribute__((ext_vector_type(4))) float  f32x4;

// ---------- helpers ----------
__device__ __forceinline__ void gll16(const void* g, void* l) {
    __builtin_amdgcn_global_load_lds(
        (const __attribute__((address_space(1))) unsigned int*)g,
        (__attribute__((address_space(3))) unsigned int*)l,
        16, 0, 0);
}

union Pack8 {
    uint4 u;
    __hip_bfloat16 h[8];
};

__device__ __forceinline__ uint4 cvt8(float4 a, float4 b) {
    Pack8 p;
    p.h[0] = __float2bfloat16(a.x); p.h[1] = __float2bfloat16(a.y);
    p.h[2] = __float2bfloat16(a.z); p.h[3] = __float2bfloat16(a.w);
    p.h[4] = __float2bfloat16(b.x); p.h[5] = __float2bfloat16(b.y);
    p.h[6] = __float2bfloat16(b.z); p.h[7] = __float2bfloat16(b.w);
    return p.u;
}

// ---------- kernel 1: W_enc fp32 -> bf16 ----------
__global__ void k_convert(const float* __restrict__ W, u16* __restrict__ Wb) {
    int idx = blockIdx.x * 256 + threadIdx.x;
    const float4* s = (const float4*)W + (size_t)idx * 2;
    ((uint4*)Wb)[idx] = cvt8(s[0], s[1]);
}

// ---------- kernel 2: att2[b,a] = dec[b,:].W_dec[a,:] + b_enc[a] + b_dec[a] ----------
__global__ void k_att2(const float* __restrict__ dec, const float* __restrict__ Wd,
                       const float* __restrict__ b_enc, const float* __restrict__ b_dec,
                       float* __restrict__ att2f) {
    int b = blockIdx.x;
    int t = threadIdx.x;
    __shared__ float dec_s[DEC_DIM];
    ((float2*)dec_s)[t] = ((const float2*)(dec + (size_t)b * DEC_DIM))[t];
    __syncthreads();
    #pragma unroll
    for (int rep = 0; rep < 2; ++rep) {
        int a = t + rep * 256;
        const float4* w = (const float4*)(Wd + (size_t)a * DEC_DIM);
        float acc = 0.f;
        #pragma unroll 4
        for (int e = 0; e < DEC_DIM / 4; ++e) {
            float4 wv = w[e];
            float4 dv = ((const float4*)dec_s)[e];
            acc += wv.x * dv.x + wv.y * dv.y + wv.z * dv.z + wv.w * dv.w;
        }
        att2f[(size_t)b * ATT_DIM + a] = acc + b_enc[a] + b_dec[a];
    }
}

// ---------- kernel 3: fused GEMM + FULL att + exp + weighted partials ----------
// Main loop: R11 structure verbatim (BN=512, BM=128, dbuf, 3-deep A prefetch,
// one barrier/tile, counted vmcnt). NEW epilogue: BN=512 => block owns the
// complete att row; computes e=exp(att) (no max needed: |att|<~5, fp32-safe,
// softmax shift-invariant), re-reads its L2/L3-warm A-panel, accumulates
// per-batch-segment partials  sum_r e_r * enc[r,:]  (block spans <=2 batches).
// k_combine normalizes. k_soft (411MB enc re-read) is ELIMINATED.

#define FENCE  asm volatile("" ::: "memory")
#define LGKM0  asm volatile("s_waitcnt lgkmcnt(0)" ::: "memory")
#define VMC(N) asm volatile("s_waitcnt vmcnt(" #N ")" ::: "memory")
#define SBARF  do { FENCE; __builtin_amdgcn_s_barrier(); FENCE; } while (0)

#define ISSUE_A(KT, F) do { const float* _p = a_src + (size_t)(KT) * 64;               \
    F[0] = *(const float4*)(_p);                                                       \
    F[1] = *(const float4*)(_p + 4);                                                   \
    F[2] = *(const float4*)(_p + (size_t)64 * ENC_DIM);                                \
    F[3] = *(const float4*)(_p + (size_t)64 * ENC_DIM + 4); } while (0)

#define WRITE_A(Q, F) do {                                                             \
    *(uint4*)(&As[Q][aw_off])        = cvt8(F[0], F[1]);                               \
    *(uint4*)(&As[Q][aw_off + 4096]) = cvt8(F[2], F[3]); } while (0)

#define STAGE_B(KT, Q) do { const u16* _b = b_src + (size_t)(KT) * 64;                 \
    _Pragma("unroll") for (int s = 0; s < 8; ++s)                                      \
        gll16(_b + (size_t)s * 64 * ENC_DIM, &Bs[Q][s * 4096 + b_dst]); } while (0)

#define COMPUTE(P) do {                                                                \
    _Pragma("unroll") for (int ks = 0; ks < 2; ++ks) {                                 \
        const int _axo = ks ? axo1 : axo0;                                             \
        bf16x8 af[4], bf[8];                                                           \
        _Pragma("unroll") for (int m = 0; m < 4; ++m)                                  \
            af[m] = *(const bf16x8*)(&As[P][a_row_off + m * 1024 + _axo]);             \
        _Pragma("unroll") for (int n = 0; n < 8; ++n)                                  \
            bf[n] = *(const bf16x8*)(&Bs[P][b_row_off + n * 1024 + _axo]);             \
        __builtin_amdgcn_s_setprio(1);                                                 \
        _Pragma("unroll") for (int m = 0; m < 4; ++m)                                  \
            _Pragma("unroll") for (int n = 0; n < 8; ++n)                              \
                acc[m][n] = __builtin_amdgcn_mfma_f32_16x16x32_bf16(af[m], bf[n], acc[m][n], 0, 0, 0); \
        __builtin_amdgcn_s_setprio(0);                                                 \
    } } while (0)

__global__ void __launch_bounds__(512, 1)
k_gemm(const float* __restrict__ enc, const u16* __restrict__ Wb,
       const float* __restrict__ att2f, const float* __restrict__ Wfull,
       float* __restrict__ exp_att, float* __restrict__ part_vec,
       float* __restrict__ part_sum) {
    const int mb = blockIdx.x;                 // 392 blocks, BN covers all of N
    const int t  = threadIdx.x;
    const int lane = t & 63, wave = t >> 6;
    const int wm = wave >> 2, wn = wave & 3;   // 2M x 4N wave grid
    const int fr = lane & 15, fq = lane >> 4;

    __shared__ u16 As[2][128 * 64];  // 2 x 16 KB
    __shared__ u16 Bs[2][512 * 64];  // 2 x 64 KB  (total LDS 160 KB exact)

    f32x4 acc[4][8];
    #pragma unroll
    for (int m = 0; m < 4; ++m)
        #pragma unroll
        for (int n = 0; n < 8; ++n)
            acc[m][n] = (f32x4){0.f, 0.f, 0.f, 0.f};

    // A staging: thread t covers rows {0,64} + (t>>3), k-octet t&7
    const int arow  = t >> 3;        // 0..63
    const int aslot = t & 7;
    const float* a_src = enc + (size_t)(mb * 128 + arow) * ENC_DIM + aslot * 8;
    const int aw_off = arow * 64 + ((aslot ^ (arow & 7))) * 8;   // +4096 for row+64

    // B staging via gll16: pre-swizzled source (rule #21), linear dest
    const int brl = lane >> 3, bslot = lane & 7;
    const u16* b_src = Wb + (size_t)(wave * 8 + brl) * ENC_DIM + ((bslot ^ brl)) * 8;
    const int b_dst = (wave * 8) * 64;

    // fragment reads: slot = ((ks<<2)|fq) ^ (fr&7)
    const int r7 = fr & 7;
    const int axo0 = ((fq    ) ^ r7) * 8;
    const int axo1 = ((fq | 4) ^ r7) * 8;
    const int a_row_off = (wm * 64 + fr) * 64;
    const int b_row_off = (wn * 128 + fr) * 64;

    float4 eE[4], eO[4];   // 2 register sets carry a 3-deep A pipeline (rule #20)

    // ---- prologue: A(0) staged; A(1),A(2) issued (2 tiles in flight) ----
    ISSUE_A(0, eE); FENCE;
    STAGE_B(0, 0);
    WRITE_A(0, eE);
    FENCE; ISSUE_A(1, eO);
    FENCE; ISSUE_A(2, eE);
    VMC(8);                // completes gll16(0)x8; keeps A(1)+A(2)
    LGKM0;
    SBARF;

    // ---- main loop: tiles 0..27, one barrier per tile, issue A(kt+3) ----
    for (int kt = 0; kt < NT - 4; kt += 2) {
        WRITE_A(1, eO);
        STAGE_B(kt + 1, 1); FENCE;
        ISSUE_A(kt + 3, eO);
        COMPUTE(0);
        VMC(4);                        // completes A(kt+2)+gll16(kt+1); keeps A(kt+3)
        LGKM0;
        SBARF;
        WRITE_A(0, eE);
        STAGE_B(kt + 2, 0); FENCE;
        ISSUE_A(kt + 4, eE);
        COMPUTE(1);
        VMC(4);
        LGKM0;
        SBARF;
    }

    // ---- tile 28: consume A(29), issue A(31) ----
    {
        WRITE_A(1, eO);
        STAGE_B(29, 1); FENCE;
        ISSUE_A(31, eO);
        COMPUTE(0);
        VMC(4);
        LGKM0;
        SBARF;
    }
    // ---- tile 29: consume A(30) ----
    {
        WRITE_A(0, eE);
        STAGE_B(30, 0);
        COMPUTE(1);
        VMC(0);
        LGKM0;
        SBARF;
    }
    // ---- tile 30: consume A(31) ----
    {
        WRITE_A(1, eO);
        STAGE_B(31, 1);
        COMPUTE(0);
        VMC(0);
        LGKM0;
        SBARF;
    }
    // ---- tile 31: pure compute ----
    COMPUTE(1);

    // ================= epilogue =================
    // Phase 1: per-wave partial row sums (over its 128 cols) -> LDS.
    // C/D layout: col = lane&15, row = (lane>>4)*4 + reg  [m89/m91]
    float* lds_f = (float*)&As[0][0];       // [4][128] att partials + [128] exp (2.5 KB, As[0] free)
    const int col_base = wn * 128 + fr;
    const int rloc = wm * 64 + fq * 4;      // local row base
    float wf[8];
    #pragma unroll
    for (int n = 0; n < 8; ++n) wf[n] = Wfull[col_base + n * 16];

    #pragma unroll
    for (int m = 0; m < 4; ++m) {
        #pragma unroll
        for (int r = 0; r < 4; ++r) {
            const int grow = mb * 128 + rloc + m * 16 + r;
            const float* a2 = att2f + (size_t)(grow / PIX) * ATT_DIM;
            float ssum = 0.f;
            #pragma unroll
            for (int n = 0; n < 8; ++n) {
                float v = acc[m][n][r] + a2[col_base + n * 16];
                v = fmaxf(v, 0.f);
                ssum += v * wf[n];
            }
            #pragma unroll
            for (int off = 1; off < 16; off <<= 1)
                ssum += __shfl_xor(ssum, off, 64);
            if (fr == 0)
                lds_f[wn * 128 + rloc + m * 16 + r] = ssum;
        }
    }
    SBARF;

    // Phase 2: full att row, exp (no max: |att| small, shift-invariant)
    const int b0    = (128 * mb) / PIX;                       // first batch in block
    const int split = min(128, PIX * (b0 + 1) - 128 * mb);    // rows [0,split)->b0, rest->b0+1
    if (t < 128) {
        float a = lds_f[t] + lds_f[128 + t] + lds_f[256 + t] + lds_f[384 + t];
        float e = __expf(a);
        lds_f[512 + t] = e;
        exp_att[(size_t)mb * 128 + t] = e;
    }
    SBARF;
    if (t < 2) {
        const int lo = t ? split : 0, hi = t ? 128 : split;
        float s = 0.f;
        for (int r = lo; r < hi; ++r) s += lds_f[512 + r];
        part_sum[mb * 2 + t] = s;
    }

    // Phase 3: weighted accumulation over the block's (L2/L3-warm) A-panel.
    // thread t owns 4 cols; rows split into the two batch segments.
    const float* erow = enc + (size_t)(mb * 128) * ENC_DIM + t * 4;
    float4 s0 = {0.f, 0.f, 0.f, 0.f}, s1 = {0.f, 0.f, 0.f, 0.f};
    for (int r = 0; r < split; ++r) {
        float e = lds_f[512 + r];
        float4 x = *(const float4*)(erow + (size_t)r * ENC_DIM);
        s0.x += e * x.x; s0.y += e * x.y; s0.z += e * x.z; s0.w += e * x.w;
    }
    for (int r = split; r < 128; ++r) {
        float e = lds_f[512 + r];
        float4 x = *(const float4*)(erow + (size_t)r * ENC_DIM);
        s1.x += e * x.x; s1.y += e * x.y; s1.z += e * x.z; s1.w += e * x.w;
    }
    *(float4*)&part_vec[((size_t)mb * 2 + 0) * ENC_DIM + t * 4] = s0;
    *(float4*)&part_vec[((size_t)mb * 2 + 1) * ENC_DIM + t * 4] = s1;
}

// ---------- kernel 4: combine partials -> atten_w_enc + alpha ----------
__global__ void k_combine(const float* __restrict__ exp_att,
                          const float* __restrict__ part_vec,
                          const float* __restrict__ part_sum,
                          float* __restrict__ out) {
    const int b = blockIdx.x;
    const int t = threadIdx.x;
    const int row0 = b * PIX;
    const int mb_lo = row0 >> 7;
    const int mb_hi = (row0 + PIX - 1) >> 7;

    float Z = 0.f;
    for (int mb = mb_lo; mb <= mb_hi; ++mb) {
        int seg = b - ((mb << 7) / PIX);
        if (seg >= 0 && seg < 2) Z += part_sum[mb * 2 + seg];
    }
    const float invZ = 1.f / Z;

    #pragma unroll
    for (int c = 0; c < 2; ++c) {
        const int e0 = t * 8 + c * 4;
        float4 s = {0.f, 0.f, 0.f, 0.f};
        for (int mb = mb_lo; mb <= mb_hi; ++mb) {
            int seg = b - ((mb << 7) / PIX);
            if (seg < 0 || seg > 1) continue;
            float4 v = *(const float4*)&part_vec[((size_t)mb * 2 + seg) * ENC_DIM + e0];
            s.x += v.x; s.y += v.y; s.z += v.z; s.w += v.w;
        }
        s.x *= invZ; s.y *= invZ; s.z *= invZ; s.w *= invZ;
        *(float4*)&out[(size_t)b * ENC_DIM + e0] = s;
    }
    if (t < PIX)
        out[(size_t)BATCH * ENC_DIM + row0 + t] = exp_att[row0 + t] * invZ;
}

extern "C" void kernel_launch(void* const* d_in, const int* in_sizes, int n_in,
                              void* d_out, int out_size, void* d_ws, size_t ws_size,
                              hipStream_t stream) {
    const float* enc    = (const float*)d_in[0];
    const float* dec    = (const float*)d_in[1];
    const float* W_enc  = (const float*)d_in[2];
    const float* b_enc  = (const float*)d_in[3];
    const float* W_dec  = (const float*)d_in[4];
    const float* b_dec  = (const float*)d_in[5];
    const float* W_full = (const float*)d_in[6];
    // d_in[7] (b_full) unused: softmax is shift-invariant, att is not an output.

    char* ws = (char*)d_ws;
    u16*   Wb       = (u16*)ws;                          // 2 MB bf16 W_enc
    float* att2f    = (float*)(ws + 2097152);            // 512 KB
    float* exp_att  = (float*)(ws + 2621440);            // 200 KB
    float* part_sum = (float*)(ws + 2883584);            // 3.1 KB
    float* part_vec = (float*)(ws + 2887680);            // 6.4 MB

    hipLaunchKernelGGL(k_convert, dim3(512), dim3(256), 0, stream, W_enc, Wb);
    hipLaunchKernelGGL(k_att2,    dim3(256), dim3(256), 0, stream, dec, W_dec, b_enc, b_dec, att2f);
    hipLaunchKernelGGL(k_gemm,    dim3(392), dim3(512), 0, stream, enc, Wb, att2f, W_full,
                       exp_att, part_vec, part_sum);
    hipLaunchKernelGGL(k_combine, dim3(256), dim3(256), 0, stream, exp_att, part_vec, part_sum,
                       (float*)d_out);
}